// Round 1
// baseline (62425.116 us; speedup 1.0000x reference)
//
#include <hip/hip_runtime.h>
#include <math.h>

#define NN 2000
#define BB 32
#define TT 24
#define T_OUT 12
#define HH 64
#define DD 10

// ---------------- workspace layout (floats) ----------------
constexpr size_t A_OFF  = 0;
constexpr size_t A_SZ   = (size_t)NN * NN;          // 4,000,000
constexpr size_t AX_OFF = A_OFF + A_SZ;
constexpr size_t AX_SZ  = (size_t)BB * TT * NN;     // 1,536,000
constexpr size_t S_SZ   = (size_t)BB * NN * HH;     // 4,096,000
constexpr size_t H0_OFF  = AX_OFF + AX_SZ;
constexpr size_t H1_OFF  = H0_OFF + S_SZ;
constexpr size_t AH0_OFF = H1_OFF + S_SZ;
constexpr size_t AH1_OFF = AH0_OFF + S_SZ;
constexpr size_t ARH_OFF = AH1_OFF + S_SZ;
constexpr size_t Z_OFF   = ARH_OFF + S_SZ;
constexpr size_t RH_OFF  = Z_OFF + S_SZ;

__device__ __forceinline__ float sigmoidf_(float x) { return 1.f / (1.f + expf(-x)); }

// ---------------- A = row_softmax(relu(E E^T)) ----------------
__global__ __launch_bounds__(256) void compute_A_kernel(const float* __restrict__ E,
                                                        float* __restrict__ A) {
    const int row = blockIdx.x;
    const int tid = threadIdx.x;
    float er[DD];
#pragma unroll
    for (int d = 0; d < DD; ++d) er[d] = E[row * DD + d];
    __shared__ float red[8];

    // pass 1: relu(dot), local max
    float lmax = -1e30f;
    for (int c = tid; c < NN; c += 256) {
        float s = 0.f;
#pragma unroll
        for (int d = 0; d < DD; ++d) s += er[d] * E[c * DD + d];
        s = fmaxf(s, 0.f);
        A[(size_t)row * NN + c] = s;
        lmax = fmaxf(lmax, s);
    }
#pragma unroll
    for (int o = 32; o > 0; o >>= 1) lmax = fmaxf(lmax, __shfl_down(lmax, o, 64));
    if ((tid & 63) == 0) red[tid >> 6] = lmax;
    __syncthreads();
    const float rmax = fmaxf(fmaxf(red[0], red[1]), fmaxf(red[2], red[3]));
    __syncthreads();

    // pass 2: exp, local sum
    float lsum = 0.f;
    for (int c = tid; c < NN; c += 256) {
        float v = expf(A[(size_t)row * NN + c] - rmax);
        A[(size_t)row * NN + c] = v;
        lsum += v;
    }
#pragma unroll
    for (int o = 32; o > 0; o >>= 1) lsum += __shfl_down(lsum, o, 64);
    if ((tid & 63) == 0) red[4 + (tid >> 6)] = lsum;
    __syncthreads();
    const float inv = 1.f / (red[4] + red[5] + red[6] + red[7]);
    for (int c = tid; c < NN; c += 256) A[(size_t)row * NN + c] *= inv;
}

// ---------------- Ax[b,t,n] = sum_m A[n,m] x[b,t,m] ----------------
__global__ __launch_bounds__(256) void ax_kernel(const float* __restrict__ A,
                                                 const float* __restrict__ x,
                                                 float* __restrict__ Ax) {
    __shared__ float As[64][65];
    __shared__ float xs[64][25];
    const int n0 = blockIdx.x * 64;
    const int b = blockIdx.y;
    const int tid = threadIdx.x;
    float acc[6] = {0, 0, 0, 0, 0, 0};
    for (int m0 = 0; m0 < NN; m0 += 64) {
#pragma unroll
        for (int l = 0; l < 16; ++l) {
            int idx = tid + l * 256;
            int r = idx >> 6, c = idx & 63;
            int n = n0 + r, m = m0 + c;
            As[r][c] = (n < NN && m < NN) ? A[(size_t)n * NN + m] : 0.f;
        }
        for (int idx = tid; idx < 64 * TT; idx += 256) {
            int c = idx >> 6, r = idx & 63;  // r fast -> coalesced over m
            int m = m0 + r;
            xs[r][c] = (m < NN) ? x[((size_t)b * TT + c) * NN + m] : 0.f;
        }
        __syncthreads();
#pragma unroll 4
        for (int mm = 0; mm < 64; ++mm) {
#pragma unroll
            for (int j = 0; j < 6; ++j) {
                int oi = tid + j * 256;
                int r = oi / TT, c = oi % TT;
                acc[j] += As[r][mm] * xs[mm][c];
            }
        }
        __syncthreads();
    }
#pragma unroll
    for (int j = 0; j < 6; ++j) {
        int oi = tid + j * 256;
        int r = oi / TT, c = oi % TT;
        int n = n0 + r;
        if (n < NN) Ax[((size_t)b * TT + c) * NN + n] = acc[j];
    }
}

// ---------------- Y[b,n,c] = sum_m A[n,m] * X[b,m,c], C=64 ----------------
__global__ __launch_bounds__(256) void gemm_Ah(const float* __restrict__ A,
                                               const float* __restrict__ X,
                                               float* __restrict__ Y) {
    __shared__ float AsT[64][68];  // [m_local][row], rows float4-readable
    __shared__ float Xs[64][68];   // [m_local][col]
    const int n0 = blockIdx.x * 64;
    const int b = blockIdx.y;
    const int tid = threadIdx.x;
    const int tr = tid >> 4;   // 0..15 row group (4 rows)
    const int tc = tid & 15;   // 0..15 col group (4 cols)
    float acc[4][4] = {};
    const float* __restrict__ Xb = X + (size_t)b * NN * HH;

    for (int m0 = 0; m0 < NN; m0 += 64) {
#pragma unroll
        for (int l = 0; l < 16; ++l) {
            int idx = tid + l * 256;
            int r = idx >> 6, c = idx & 63;  // c fast: coalesced over A cols
            int n = n0 + r, m = m0 + c;
            AsT[c][r] = (n < NN && m < NN) ? A[(size_t)n * NN + m] : 0.f;
        }
#pragma unroll
        for (int l = 0; l < 16; ++l) {
            int idx = tid + l * 256;
            int r = idx >> 6, c = idx & 63;  // c fast: coalesced over channels
            int m = m0 + r;
            Xs[r][c] = (m < NN) ? Xb[(size_t)m * HH + c] : 0.f;
        }
        __syncthreads();
#pragma unroll 8
        for (int mm = 0; mm < 64; ++mm) {
            float4 av = *(const float4*)&AsT[mm][tr * 4];
            float4 bv = *(const float4*)&Xs[mm][tc * 4];
            float a[4] = {av.x, av.y, av.z, av.w};
            float bq[4] = {bv.x, bv.y, bv.z, bv.w};
#pragma unroll
            for (int i = 0; i < 4; ++i)
#pragma unroll
                for (int j = 0; j < 4; ++j) acc[i][j] += a[i] * bq[j];
        }
        __syncthreads();
    }
#pragma unroll
    for (int i = 0; i < 4; ++i) {
        int n = n0 + tr * 4 + i;
        if (n < NN) {
            float4 v = make_float4(acc[i][0], acc[i][1], acc[i][2], acc[i][3]);
            *(float4*)&Y[((size_t)b * NN + n) * HH + tc * 4] = v;
        }
    }
}

// ---------------- NAPL gconv (gate or candidate) ----------------
// One block per node (blockIdx.x = n). For GATE, blockIdx.y = part (0 -> z, 1 -> r).
// out[b,o] = bias[n,o] + sum_i in[b,n,i]*W[n,0,i,o] + sum_i Ain[b,n,i]*W[n,1,i,o]
// with W[n,k,i,o] = sum_d emb[n,d] * Wp[d,k,i,o], built in LDS per block.
template <int C1, int C2, bool XS, bool GATE>
__global__ __launch_bounds__(256) void napl_kernel(
    const float* __restrict__ emb, const float* __restrict__ Wp,
    const float* __restrict__ bp, const float* __restrict__ in1,
    const float* __restrict__ in1A, const float* __restrict__ in2,
    const float* __restrict__ in2A, float* __restrict__ zbuf,
    float* __restrict__ out2,  // GATE: rh output; CAND: h state (in/out)
    int t) {
    constexpr int CI = C1 + C2;
    constexpr int CO = GATE ? 2 * HH : HH;
    static_assert(C2 == HH, "gate epilogue assumes C2==64");
    const int n = blockIdx.x;
    const int part = GATE ? blockIdx.y : 0;
    const int tid = threadIdx.x;

    __shared__ float Wl[2][CI][64];
    __shared__ float bl[64];
    __shared__ float es[DD];
    if (tid < DD) es[tid] = emb[n * DD + tid];
    __syncthreads();

    // build this node's weights in LDS
    for (int idx = tid; idx < 2 * CI * 64; idx += 256) {
        int k = idx / (CI * 64);
        int rem = idx - k * CI * 64;
        int i = rem >> 6;
        int o = rem & 63;
        float s = 0.f;
#pragma unroll
        for (int d = 0; d < DD; ++d)
            s += es[d] * Wp[((size_t)(d * 2 + k) * CI + i) * CO + part * 64 + o];
        Wl[k][i][o] = s;
    }
    if (tid < 64) {
        float s = 0.f;
#pragma unroll
        for (int d = 0; d < DD; ++d) s += es[d] * bp[d * CO + part * 64 + tid];
        bl[tid] = s;
    }
    __syncthreads();

    const int oq = tid & 15;  // o = oq*4 .. oq*4+3
    const int bb = tid >> 4;  // b in {bb, bb+16}
    float acc[2][4];
#pragma unroll
    for (int u = 0; u < 2; ++u)
#pragma unroll
        for (int j = 0; j < 4; ++j) acc[u][j] = 0.f;

#pragma unroll 1
    for (int i = 0; i < C1; ++i) {
        float4 w0 = *(const float4*)&Wl[0][i][oq * 4];
        float4 w1 = *(const float4*)&Wl[1][i][oq * 4];
#pragma unroll
        for (int u = 0; u < 2; ++u) {
            const int b = bb + u * 16;
            float v, va;
            if (XS) {
                size_t ix = ((size_t)b * TT + t) * NN + n;
                v = in1[ix];
                va = in1A[ix];
            } else {
                size_t ix = ((size_t)b * NN + n) * C1 + i;
                v = in1[ix];
                va = in1A[ix];
            }
            acc[u][0] += v * w0.x + va * w1.x;
            acc[u][1] += v * w0.y + va * w1.y;
            acc[u][2] += v * w0.z + va * w1.z;
            acc[u][3] += v * w0.w + va * w1.w;
        }
    }
#pragma unroll 2
    for (int i2 = 0; i2 < C2; ++i2) {
        const int i = C1 + i2;
        float4 w0 = *(const float4*)&Wl[0][i][oq * 4];
        float4 w1 = *(const float4*)&Wl[1][i][oq * 4];
#pragma unroll
        for (int u = 0; u < 2; ++u) {
            const int b = bb + u * 16;
            size_t ix = ((size_t)b * NN + n) * C2 + i2;
            float v = in2[ix];
            float va = in2A[ix];
            acc[u][0] += v * w0.x + va * w1.x;
            acc[u][1] += v * w0.y + va * w1.y;
            acc[u][2] += v * w0.z + va * w1.z;
            acc[u][3] += v * w0.w + va * w1.w;
        }
    }

#pragma unroll
    for (int u = 0; u < 2; ++u) {
        const int b = bb + u * 16;
        const size_t base = ((size_t)b * NN + n) * HH + oq * 4;
#pragma unroll
        for (int j = 0; j < 4; ++j) {
            float val = acc[u][j] + bl[oq * 4 + j];
            if (GATE) {
                float s = sigmoidf_(val);
                if (part == 0) {
                    zbuf[base + j] = s;        // z
                } else {
                    out2[base + j] = s * in2[base + j];  // rh = r * h
                }
            } else {
                float hc = tanhf(val);
                float z = zbuf[base + j];
                float hp = out2[base + j];
                out2[base + j] = z * hp + (1.f - z) * hc;
            }
        }
    }
}

// ---------------- head: y[b,ot,n] = hb[ot] + sum_h h1[b,n,h]*hw[ot,h] ----------------
__global__ __launch_bounds__(256) void head_kernel(const float* __restrict__ h1,
                                                   const float* __restrict__ hw,
                                                   const float* __restrict__ hb,
                                                   float* __restrict__ y) {
    __shared__ float wl[T_OUT * HH];
    const int tid = threadIdx.x;
    for (int idx = tid; idx < T_OUT * HH; idx += 256) wl[idx] = hw[idx];
    __syncthreads();
    const int gi = blockIdx.x * 256 + tid;
    if (gi >= BB * NN) return;
    const int b = gi / NN, n = gi % NN;
    float acc[T_OUT];
#pragma unroll
    for (int ot = 0; ot < T_OUT; ++ot) acc[ot] = hb[ot];
    for (int h = 0; h < HH; ++h) {
        float v = h1[((size_t)b * NN + n) * HH + h];
#pragma unroll
        for (int ot = 0; ot < T_OUT; ++ot) acc[ot] += v * wl[ot * HH + h];
    }
#pragma unroll
    for (int ot = 0; ot < T_OUT; ++ot)
        y[((size_t)b * T_OUT + ot) * NN + n] = acc[ot];
}

extern "C" void kernel_launch(void* const* d_in, const int* in_sizes, int n_in,
                              void* d_out, int out_size, void* d_ws, size_t ws_size,
                              hipStream_t stream) {
    const float* x = (const float*)d_in[0];
    const float* node_emb = (const float*)d_in[1];
    const float* adapt_emb = (const float*)d_in[2];
    const float* Wg0 = (const float*)d_in[3];
    const float* bg0 = (const float*)d_in[4];
    const float* Wc0 = (const float*)d_in[5];
    const float* bc0 = (const float*)d_in[6];
    const float* Wg1 = (const float*)d_in[7];
    const float* bg1 = (const float*)d_in[8];
    const float* Wc1 = (const float*)d_in[9];
    const float* bc1 = (const float*)d_in[10];
    const float* head_w = (const float*)d_in[11];
    const float* head_b = (const float*)d_in[12];
    float* y = (float*)d_out;

    float* ws = (float*)d_ws;
    float* A = ws + A_OFF;
    float* Ax = ws + AX_OFF;
    float* h0 = ws + H0_OFF;
    float* h1 = ws + H1_OFF;
    float* Ah0 = ws + AH0_OFF;
    float* Ah1 = ws + AH1_OFF;
    float* Arh = ws + ARH_OFF;
    float* z = ws + Z_OFF;
    float* rh = ws + RH_OFF;

    hipMemsetAsync(h0, 0, S_SZ * sizeof(float), stream);
    hipMemsetAsync(h1, 0, S_SZ * sizeof(float), stream);

    compute_A_kernel<<<NN, 256, 0, stream>>>(adapt_emb, A);

    dim3 gGemm((NN + 63) / 64, BB);
    ax_kernel<<<gGemm, 256, 0, stream>>>(A, x, Ax);

    for (int t = 0; t < TT; ++t) {
        gemm_Ah<<<gGemm, 256, 0, stream>>>(A, h0, Ah0);
        gemm_Ah<<<gGemm, 256, 0, stream>>>(A, h1, Ah1);
        // layer 0 gate: inp = [x_t, h0], z & rh0
        napl_kernel<1, HH, true, true><<<dim3(NN, 2), 256, 0, stream>>>(
            node_emb, Wg0, bg0, x, Ax, h0, Ah0, z, rh, t);
        gemm_Ah<<<gGemm, 256, 0, stream>>>(A, rh, Arh);
        // layer 0 candidate: inp = [x_t, rh0], updates h0
        napl_kernel<1, HH, true, false><<<dim3(NN, 1), 256, 0, stream>>>(
            node_emb, Wc0, bc0, x, Ax, rh, Arh, z, h0, t);
        gemm_Ah<<<gGemm, 256, 0, stream>>>(A, h0, Ah0);  // A @ h0_new
        // layer 1 gate: inp = [h0_new, h1]
        napl_kernel<HH, HH, false, true><<<dim3(NN, 2), 256, 0, stream>>>(
            node_emb, Wg1, bg1, h0, Ah0, h1, Ah1, z, rh, t);
        gemm_Ah<<<gGemm, 256, 0, stream>>>(A, rh, Arh);
        // layer 1 candidate: inp = [h0_new, rh1], updates h1
        napl_kernel<HH, HH, false, false><<<dim3(NN, 1), 256, 0, stream>>>(
            node_emb, Wc1, bc1, h0, Ah0, rh, Arh, z, h1, t);
    }

    head_kernel<<<(BB * NN + 255) / 256, 256, 0, stream>>>(h1, head_w, head_b, y);
}

// Round 2
// 18003.801 us; speedup vs baseline: 3.4673x; 3.4673x over previous
//
#include <hip/hip_runtime.h>
#include <math.h>

#define NN 2000
#define BB 32
#define TT 24
#define T_OUT 12
#define HH 64
#define DD 10
#define NP 2048   // padded node dim
#define BC 2048   // B*H columns

typedef unsigned short ushort_t;
typedef __bf16 bf16x8 __attribute__((ext_vector_type(8)));
typedef float f32x4 __attribute__((ext_vector_type(4)));

__device__ __forceinline__ float sigmoidf_(float x) { return 1.f / (1.f + expf(-x)); }

__device__ __forceinline__ ushort_t f2bf(float f) {
    unsigned int u = __float_as_uint(f);
    unsigned int r = (u + 0x7FFFu + ((u >> 16) & 1u)) >> 16;
    return (ushort_t)r;
}
__device__ __forceinline__ float bf2f(ushort_t s) {
    return __uint_as_float(((unsigned int)s) << 16);
}

// ---------------- workspace layout (bytes) ----------------
constexpr size_t ABF_OFF = 0;                         // [2048][2048] bf16
constexpr size_t H0T_OFF = ABF_OFF + (size_t)NP * NP * 2;
constexpr size_t H1T_OFF = H0T_OFF + (size_t)NP * NP * 2;
constexpr size_t RHT_OFF = H1T_OFF + (size_t)NP * NP * 2;
constexpr size_t H0F_OFF = RHT_OFF + (size_t)NP * NP * 2;   // [2000][2048] f32
constexpr size_t H1F_OFF = H0F_OFF + (size_t)NN * BC * 4;
constexpr size_t ZF_OFF  = H1F_OFF + (size_t)NN * BC * 4;   // f32; overlaid with A_f32 scratch
constexpr size_t RHB_OFF = ZF_OFF + (size_t)NN * BC * 4;    // [2000][2048] bf16
constexpr size_t AH0_OFF = RHB_OFF + (size_t)NN * BC * 2;
constexpr size_t AH1_OFF = AH0_OFF + (size_t)NN * BC * 2;
constexpr size_t ARH_OFF = AH1_OFF + (size_t)NN * BC * 2;
constexpr size_t AXF_OFF = ARH_OFF + (size_t)NN * BC * 2;   // [B][T][N] f32

// ---------------- A_f32 = row_softmax(relu(E E^T)) ----------------
__global__ __launch_bounds__(256) void compute_A_kernel(const float* __restrict__ E,
                                                        float* __restrict__ A) {
    const int row = blockIdx.x;
    const int tid = threadIdx.x;
    float er[DD];
#pragma unroll
    for (int d = 0; d < DD; ++d) er[d] = E[row * DD + d];
    __shared__ float red[8];

    float lmax = -1e30f;
    for (int c = tid; c < NN; c += 256) {
        float s = 0.f;
#pragma unroll
        for (int d = 0; d < DD; ++d) s += er[d] * E[c * DD + d];
        s = fmaxf(s, 0.f);
        A[(size_t)row * NN + c] = s;
        lmax = fmaxf(lmax, s);
    }
#pragma unroll
    for (int o = 32; o > 0; o >>= 1) lmax = fmaxf(lmax, __shfl_down(lmax, o, 64));
    if ((tid & 63) == 0) red[tid >> 6] = lmax;
    __syncthreads();
    const float rmax = fmaxf(fmaxf(red[0], red[1]), fmaxf(red[2], red[3]));
    __syncthreads();

    float lsum = 0.f;
    for (int c = tid; c < NN; c += 256) {
        float v = expf(A[(size_t)row * NN + c] - rmax);
        A[(size_t)row * NN + c] = v;
        lsum += v;
    }
#pragma unroll
    for (int o = 32; o > 0; o >>= 1) lsum += __shfl_down(lsum, o, 64);
    if ((tid & 63) == 0) red[4 + (tid >> 6)] = lsum;
    __syncthreads();
    const float inv = 1.f / (red[4] + red[5] + red[6] + red[7]);
    for (int c = tid; c < NN; c += 256) A[(size_t)row * NN + c] *= inv;
}

// ---------------- A_f32 -> A_bf [2048][2048] with zero pad ----------------
__global__ __launch_bounds__(256) void convert_A(const float* __restrict__ Af,
                                                 ushort_t* __restrict__ Ab) {
    size_t idx = (size_t)blockIdx.x * 256 + threadIdx.x;
    int r = (int)(idx >> 11), c = (int)(idx & 2047);
    float v = (r < NN && c < NN) ? Af[(size_t)r * NN + c] : 0.f;
    Ab[idx] = f2bf(v);
}

// ---------------- Ax[b,t,n] = sum_m A[n,m] x[b,t,m]  (f32, one-time) ----------------
__global__ __launch_bounds__(256) void ax_kernel(const float* __restrict__ A,
                                                 const float* __restrict__ x,
                                                 float* __restrict__ Ax) {
    __shared__ float As[64][65];
    __shared__ float xs[64][25];
    const int n0 = blockIdx.x * 64;
    const int b = blockIdx.y;
    const int tid = threadIdx.x;
    float acc[6] = {0, 0, 0, 0, 0, 0};
    for (int m0 = 0; m0 < NN; m0 += 64) {
#pragma unroll
        for (int l = 0; l < 16; ++l) {
            int idx = tid + l * 256;
            int r = idx >> 6, c = idx & 63;
            int n = n0 + r, m = m0 + c;
            As[r][c] = (n < NN && m < NN) ? A[(size_t)n * NN + m] : 0.f;
        }
        for (int idx = tid; idx < 64 * TT; idx += 256) {
            int c = idx >> 6, r = idx & 63;
            int m = m0 + r;
            xs[r][c] = (m < NN) ? x[((size_t)b * TT + c) * NN + m] : 0.f;
        }
        __syncthreads();
#pragma unroll 4
        for (int mm = 0; mm < 64; ++mm) {
#pragma unroll
            for (int j = 0; j < 6; ++j) {
                int oi = tid + j * 256;
                int r = oi / TT, c = oi % TT;
                acc[j] += As[r][mm] * xs[mm][c];
            }
        }
        __syncthreads();
    }
#pragma unroll
    for (int j = 0; j < 6; ++j) {
        int oi = tid + j * 256;
        int r = oi / TT, c = oi % TT;
        int n = n0 + r;
        if (n < NN) Ax[((size_t)b * TT + c) * NN + n] = acc[j];
    }
}

// ---------------- transpose state [n][j] -> [j][n] bf16, zero-fill n>=NN ----------------
template <bool SRC_F32>
__global__ __launch_bounds__(256) void transpose_to_bf(const void* __restrict__ src,
                                                       ushort_t* __restrict__ dst) {
    __shared__ float tile[64][65];
    const int jb = blockIdx.x * 64, nb = blockIdx.y * 64;
    const int tid = threadIdx.x;
#pragma unroll
    for (int l = 0; l < 16; ++l) {
        int idx = tid + l * 256;
        int r = idx >> 6, c = idx & 63;  // r: n-local, c: j-local
        int n = nb + r;
        float v = 0.f;
        if (n < NN)
            v = SRC_F32 ? ((const float*)src)[(size_t)n * BC + jb + c]
                        : bf2f(((const ushort_t*)src)[(size_t)n * BC + jb + c]);
        tile[r][c] = v;
    }
    __syncthreads();
#pragma unroll
    for (int l = 0; l < 16; ++l) {
        int idx = tid + l * 256;
        int r = idx >> 6, c = idx & 63;  // r: j-local, c: n-local
        dst[(size_t)(jb + r) * NP + nb + c] = f2bf(tile[c][r]);
    }
}

// ---------------- MFMA GEMM: Y[n][j] = sum_m A[n][m] * XT[j][m], bf16 ----------------
// A: [2048][2048] bf16 row-major; XT: [2048][2048] bf16 row-major (j rows).
// Output Y: [2000][2048] bf16. 128x128 tile, BK=32, 4 waves, m97 structure.
__global__ __launch_bounds__(256) void gemm_mfma(const ushort_t* __restrict__ Ab,
                                                 const ushort_t* __restrict__ XT,
                                                 ushort_t* __restrict__ Y) {
    __shared__ ushort_t As[128 * 32];
    __shared__ ushort_t Bs[128 * 32];
    const int tid = threadIdx.x;
    const int w = tid >> 6, l = tid & 63;
    const int n0 = blockIdx.x * 128, j0 = blockIdx.y * 128;
    const int wm = w & 1, wj = w >> 1;
    const int lr = l & 15, lg = l >> 4;
    f32x4 acc[4][4] = {};

    const char* Abase = (const char*)Ab;
    const char* Bbase = (const char*)XT;

    for (int ks = 0; ks < NP / 32; ++ks) {
        const int k0 = ks * 32;
#pragma unroll
        for (int p = 0; p < 2; ++p) {
            const int o = p * 4096 + w * 1024 + l * 16;  // byte offset in 8KB tile
            const int row = o >> 6, colb = o & 63;       // 64B per LDS row (32 bf16)
            __builtin_amdgcn_global_load_lds(
                (const __attribute__((address_space(1))) char*)(Abase + (size_t)(n0 + row) * (NP * 2) + k0 * 2 + colb),
                (__attribute__((address_space(3))) char*)((char*)As + o), 16, 0, 0);
            __builtin_amdgcn_global_load_lds(
                (const __attribute__((address_space(1))) char*)(Bbase + (size_t)(j0 + row) * (NP * 2) + k0 * 2 + colb),
                (__attribute__((address_space(3))) char*)((char*)Bs + o), 16, 0, 0);
        }
        __syncthreads();

        bf16x8 af[4], bf[4];
#pragma unroll
        for (int mt = 0; mt < 4; ++mt)
            af[mt] = *(const bf16x8*)&As[(wm * 64 + mt * 16 + lr) * 32 + lg * 8];
#pragma unroll
        for (int nt = 0; nt < 4; ++nt)
            bf[nt] = *(const bf16x8*)&Bs[(wj * 64 + nt * 16 + lr) * 32 + lg * 8];
#pragma unroll
        for (int mt = 0; mt < 4; ++mt)
#pragma unroll
            for (int nt = 0; nt < 4; ++nt)
                acc[mt][nt] = __builtin_amdgcn_mfma_f32_16x16x32_bf16(af[mt], bf[nt], acc[mt][nt], 0, 0, 0);
        __syncthreads();
    }

#pragma unroll
    for (int mt = 0; mt < 4; ++mt) {
#pragma unroll
        for (int r = 0; r < 4; ++r) {
            const int n = n0 + wm * 64 + mt * 16 + lg * 4 + r;
            if (n < NN) {
#pragma unroll
                for (int nt = 0; nt < 4; ++nt) {
                    const int j = j0 + wj * 64 + nt * 16 + lr;
                    Y[(size_t)n * BC + j] = f2bf(acc[mt][nt][r]);
                }
            }
        }
    }
}

// ---------------- NAPL gconv (gate or candidate), per-node block ----------------
// state layout: [n][b*64+c]. GATE: grid (N,2); part0 -> z (f32), part1 -> rh (bf16).
// CAND: grid (N,1); h state f32 updated in place.
template <int C1, bool XS, bool GATE>
__global__ __launch_bounds__(256) void napl_kernel(
    const float* __restrict__ emb, const float* __restrict__ Wp,
    const float* __restrict__ bp,
    const float* __restrict__ in1,   // x (XS) or h0f
    const void* __restrict__ in1A_,  // Ax f32 (XS) or Ah0 bf16
    const void* __restrict__ in2_,   // GATE: h f32 ; CAND: rh bf16
    const ushort_t* __restrict__ in2A,
    float* __restrict__ zf,
    void* __restrict__ out2_,        // GATE: rh bf16 out ; CAND: h f32 state
    int t) {
    constexpr int CI = C1 + HH;
    constexpr int CO = GATE ? 2 * HH : HH;
    const int n = blockIdx.x;
    const int part = GATE ? blockIdx.y : 0;
    const int tid = threadIdx.x;

    __shared__ float Wl[2][CI][64];
    __shared__ float bl[64];
    __shared__ float es[DD];
    if (tid < DD) es[tid] = emb[n * DD + tid];
    __syncthreads();

    for (int idx = tid; idx < 2 * CI * 64; idx += 256) {
        int k = idx / (CI * 64);
        int rem = idx - k * CI * 64;
        int i = rem >> 6;
        int o = rem & 63;
        float s = 0.f;
#pragma unroll
        for (int d = 0; d < DD; ++d)
            s += es[d] * Wp[((size_t)(d * 2 + k) * CI + i) * CO + part * 64 + o];
        Wl[k][i][o] = s;
    }
    if (tid < 64) {
        float s = 0.f;
#pragma unroll
        for (int d = 0; d < DD; ++d) s += es[d] * bp[d * CO + part * 64 + tid];
        bl[tid] = s;
    }
    __syncthreads();

    const int oq = tid & 15;  // o = oq*4..oq*4+3
    const int bb = tid >> 4;  // b in {bb, bb+16}
    float acc[2][4];
#pragma unroll
    for (int u = 0; u < 2; ++u)
#pragma unroll
        for (int j = 0; j < 4; ++j) acc[u][j] = 0.f;

#pragma unroll 1
    for (int i = 0; i < C1; ++i) {
        float4 w0 = *(const float4*)&Wl[0][i][oq * 4];
        float4 w1 = *(const float4*)&Wl[1][i][oq * 4];
#pragma unroll
        for (int u = 0; u < 2; ++u) {
            const int b = bb + u * 16;
            float v, va;
            if (XS) {
                size_t ix = ((size_t)b * TT + t) * NN + n;
                v = in1[ix];
                va = ((const float*)in1A_)[ix];
            } else {
                size_t ix = (size_t)n * BC + b * 64 + i;
                v = in1[ix];
                va = bf2f(((const ushort_t*)in1A_)[ix]);
            }
            acc[u][0] += v * w0.x + va * w1.x;
            acc[u][1] += v * w0.y + va * w1.y;
            acc[u][2] += v * w0.z + va * w1.z;
            acc[u][3] += v * w0.w + va * w1.w;
        }
    }
#pragma unroll 2
    for (int i2 = 0; i2 < HH; ++i2) {
        const int i = C1 + i2;
        float4 w0 = *(const float4*)&Wl[0][i][oq * 4];
        float4 w1 = *(const float4*)&Wl[1][i][oq * 4];
#pragma unroll
        for (int u = 0; u < 2; ++u) {
            const int b = bb + u * 16;
            size_t ix = (size_t)n * BC + b * 64 + i2;
            float v = GATE ? ((const float*)in2_)[ix] : bf2f(((const ushort_t*)in2_)[ix]);
            float va = bf2f(in2A[ix]);
            acc[u][0] += v * w0.x + va * w1.x;
            acc[u][1] += v * w0.y + va * w1.y;
            acc[u][2] += v * w0.z + va * w1.z;
            acc[u][3] += v * w0.w + va * w1.w;
        }
    }

#pragma unroll
    for (int u = 0; u < 2; ++u) {
        const int b = bb + u * 16;
        const size_t base = (size_t)n * BC + b * 64 + oq * 4;
#pragma unroll
        for (int j = 0; j < 4; ++j) {
            float val = acc[u][j] + bl[oq * 4 + j];
            if (GATE) {
                float s = sigmoidf_(val);
                if (part == 0) {
                    zf[base + j] = s;  // z
                } else {
                    float h = ((const float*)in2_)[base + j];
                    ((ushort_t*)out2_)[base + j] = f2bf(s * h);  // rh = r*h
                }
            } else {
                float hc = tanhf(val);
                float z = zf[base + j];
                float* hs = (float*)out2_;
                float hp = hs[base + j];
                hs[base + j] = z * hp + (1.f - z) * hc;
            }
        }
    }
}

// ---------------- head: y[b,ot,n] = hb[ot] + sum_h h1[n][b*64+h]*hw[ot,h] ----------------
__global__ __launch_bounds__(256) void head_kernel(const float* __restrict__ h1,
                                                   const float* __restrict__ hw,
                                                   const float* __restrict__ hb,
                                                   float* __restrict__ y) {
    __shared__ float wl[T_OUT * HH];
    const int tid = threadIdx.x;
    for (int idx = tid; idx < T_OUT * HH; idx += 256) wl[idx] = hw[idx];
    __syncthreads();
    const int gi = blockIdx.x * 256 + tid;
    if (gi >= BB * NN) return;
    const int b = gi / NN, n = gi % NN;
    float acc[T_OUT];
#pragma unroll
    for (int ot = 0; ot < T_OUT; ++ot) acc[ot] = hb[ot];
    for (int h = 0; h < HH; ++h) {
        float v = h1[(size_t)n * BC + b * 64 + h];
#pragma unroll
        for (int ot = 0; ot < T_OUT; ++ot) acc[ot] += v * wl[ot * HH + h];
    }
#pragma unroll
    for (int ot = 0; ot < T_OUT; ++ot)
        y[((size_t)b * T_OUT + ot) * NN + n] = acc[ot];
}

extern "C" void kernel_launch(void* const* d_in, const int* in_sizes, int n_in,
                              void* d_out, int out_size, void* d_ws, size_t ws_size,
                              hipStream_t stream) {
    const float* x = (const float*)d_in[0];
    const float* node_emb = (const float*)d_in[1];
    const float* adapt_emb = (const float*)d_in[2];
    const float* Wg0 = (const float*)d_in[3];
    const float* bg0 = (const float*)d_in[4];
    const float* Wc0 = (const float*)d_in[5];
    const float* bc0 = (const float*)d_in[6];
    const float* Wg1 = (const float*)d_in[7];
    const float* bg1 = (const float*)d_in[8];
    const float* Wc1 = (const float*)d_in[9];
    const float* bc1 = (const float*)d_in[10];
    const float* head_w = (const float*)d_in[11];
    const float* head_b = (const float*)d_in[12];
    float* y = (float*)d_out;

    char* ws = (char*)d_ws;
    ushort_t* Abf = (ushort_t*)(ws + ABF_OFF);
    ushort_t* h0T = (ushort_t*)(ws + H0T_OFF);
    ushort_t* h1T = (ushort_t*)(ws + H1T_OFF);
    ushort_t* rhT = (ushort_t*)(ws + RHT_OFF);
    float* h0f = (float*)(ws + H0F_OFF);
    float* h1f = (float*)(ws + H1F_OFF);
    float* zf  = (float*)(ws + ZF_OFF);     // also A_f32 scratch during setup
    ushort_t* rhb = (ushort_t*)(ws + RHB_OFF);
    ushort_t* Ah0 = (ushort_t*)(ws + AH0_OFF);
    ushort_t* Ah1 = (ushort_t*)(ws + AH1_OFF);
    ushort_t* Arh = (ushort_t*)(ws + ARH_OFF);
    float* Axf = (float*)(ws + AXF_OFF);
    float* Af32 = zf;  // overlay: consumed before first gate writes z

    hipMemsetAsync(h0f, 0, (size_t)NN * BC * 4, stream);
    hipMemsetAsync(h1f, 0, (size_t)NN * BC * 4, stream);
    hipMemsetAsync(Ah0, 0, (size_t)NN * BC * 2, stream);
    hipMemsetAsync(h1T, 0, (size_t)NP * NP * 2, stream);

    compute_A_kernel<<<NN, 256, 0, stream>>>(adapt_emb, Af32);
    ax_kernel<<<dim3((NN + 63) / 64, BB), 256, 0, stream>>>(Af32, x, Axf);
    convert_A<<<(NP * NP) / 256, 256, 0, stream>>>(Af32, Abf);

    const dim3 gG(NP / 128, NP / 128);   // 16 x 16
    const dim3 gT(NP / 64, NP / 64);     // 32 x 32

    for (int t = 0; t < TT; ++t) {
        // Ah1 = A @ h1_prev
        gemm_mfma<<<gG, 256, 0, stream>>>(Abf, h1T, Ah1);
        // layer0 gate: in = [x_t, h0]; z & rh
        napl_kernel<1, true, true><<<dim3(NN, 2), 256, 0, stream>>>(
            node_emb, Wg0, bg0, x, Axf, h0f, Ah0, zf, rhb, t);
        transpose_to_bf<false><<<gT, 256, 0, stream>>>(rhb, rhT);
        gemm_mfma<<<gG, 256, 0, stream>>>(Abf, rhT, Arh);
        // layer0 candidate -> h0 (in place)
        napl_kernel<1, true, false><<<dim3(NN, 1), 256, 0, stream>>>(
            node_emb, Wc0, bc0, x, Axf, rhb, Arh, zf, h0f, t);
        transpose_to_bf<true><<<gT, 256, 0, stream>>>(h0f, h0T);
        gemm_mfma<<<gG, 256, 0, stream>>>(Abf, h0T, Ah0);  // A @ h0_new (reused next step)
        // layer1 gate: in = [h0_new, h1]
        napl_kernel<HH, false, true><<<dim3(NN, 2), 256, 0, stream>>>(
            node_emb, Wg1, bg1, h0f, Ah0, h1f, Ah1, zf, rhb, t);
        transpose_to_bf<false><<<gT, 256, 0, stream>>>(rhb, rhT);
        gemm_mfma<<<gG, 256, 0, stream>>>(Abf, rhT, Arh);
        // layer1 candidate -> h1 (in place)
        napl_kernel<HH, false, false><<<dim3(NN, 1), 256, 0, stream>>>(
            node_emb, Wc1, bc1, h0f, Ah0, rhb, Arh, zf, h1f, t);
        transpose_to_bf<true><<<gT, 256, 0, stream>>>(h1f, h1T);
    }

    head_kernel<<<(BB * NN + 255) / 256, 256, 0, stream>>>(h1f, head_w, head_b, y);
}